// Round 1
// baseline (877.866 us; speedup 1.0000x reference)
//
#include <hip/hip_runtime.h>
#include <math.h>

// SpatialProcessor: 2-layer GAT over top-K cosine-sim graph.
// All f32 in/out. Pipeline:
//   norm = emb/||emb||            (normalize_kernel)
//   topk[i][0..19] = argtop20_j dot(norm_i, norm_j), ties -> lower index (sim_topk_kernel)
//   h1p = x @ W1   [10000,256]    (gemm1_kernel)
//   e1s/e1t[n][h] = <h1p[n,h,:], a1_src/tgt[h,:]>  (e1_kernel)
//   h1 = relu(GAT-aggregate(h1p, edges) + b1)      (agg1_kernel)
//   h2p = h1 @ W2  [10000,64]     (gemm2_kernel)
//   e2s/e2t                       (e2_kernel)
//   out = GAT-aggregate(h2p, edges) + b2           (agg2_kernel)
// Edges for node i: topk[i][0..19] then self-loop (matches reference edge order).

#define N_NODES 10000
#define EMB_D   16
#define IN_DIM  128
#define H1      4
#define CDIM    64
#define D1      256   // 4*64
#define K_TOP   20
#define NEIGH   21    // K_TOP + self loop

__global__ __launch_bounds__(256) void normalize_kernel(
    const float* __restrict__ emb, float* __restrict__ nrm) {
  int i = blockIdx.x * 256 + threadIdx.x;
  if (i >= N_NODES) return;
  const float4* p = (const float4*)(emb + (size_t)i * EMB_D);
  float4 v[4];
  float ss = 0.f;
#pragma unroll
  for (int k = 0; k < 4; k++) {
    v[k] = p[k];
    ss = fmaf(v[k].x, v[k].x, ss);
    ss = fmaf(v[k].y, v[k].y, ss);
    ss = fmaf(v[k].z, v[k].z, ss);
    ss = fmaf(v[k].w, v[k].w, ss);
  }
  float nv = sqrtf(ss);
  float4* o = (float4*)(nrm + (size_t)i * EMB_D);
#pragma unroll
  for (int k = 0; k < 4; k++) {
    float4 t;
    t.x = v[k].x / nv; t.y = v[k].y / nv; t.z = v[k].z / nv; t.w = v[k].w / nv;
    o[k] = t;
  }
}

// One block per row i. Full sim row in LDS, then 20 rounds of block argmax.
// Key: monotonic-u32(float) << 32 | (0xFFFFFFFF - j)  => max = (largest sim, smallest j).
__global__ __launch_bounds__(256) void sim_topk_kernel(
    const float* __restrict__ nrm, int* __restrict__ topk) {
  __shared__ float s_sim[N_NODES];                 // 40000 B
  __shared__ unsigned long long s_red[256];        // 2048 B
  __shared__ float s_q[EMB_D];
  int i = blockIdx.x;
  int tid = threadIdx.x;
  if (tid < EMB_D) s_q[tid] = nrm[(size_t)i * EMB_D + tid];
  __syncthreads();
  float q[EMB_D];
#pragma unroll
  for (int k = 0; k < EMB_D; k++) q[k] = s_q[k];

  for (int j = tid; j < N_NODES; j += 256) {
    const float4* pj = (const float4*)(nrm + (size_t)j * EMB_D);
    float acc = 0.f;
#pragma unroll
    for (int k4 = 0; k4 < 4; k4++) {
      float4 v = pj[k4];
      acc = fmaf(q[4 * k4 + 0], v.x, acc);
      acc = fmaf(q[4 * k4 + 1], v.y, acc);
      acc = fmaf(q[4 * k4 + 2], v.z, acc);
      acc = fmaf(q[4 * k4 + 3], v.w, acc);
    }
    s_sim[j] = acc;
  }
  __syncthreads();

  for (int r = 0; r < K_TOP; r++) {
    unsigned long long best = 0ull;
    for (int j = tid; j < N_NODES; j += 256) {
      float v = s_sim[j];
      unsigned u = __float_as_uint(v);
      u = (u & 0x80000000u) ? ~u : (u | 0x80000000u);
      unsigned long long key =
          ((unsigned long long)u << 32) | (unsigned long long)(0xFFFFFFFFu - (unsigned)j);
      if (key > best) best = key;
    }
    s_red[tid] = best;
    __syncthreads();
#pragma unroll
    for (int s = 128; s > 0; s >>= 1) {
      if (tid < s) {
        unsigned long long o = s_red[tid + s];
        if (o > s_red[tid]) s_red[tid] = o;
      }
      __syncthreads();
    }
    if (tid == 0) {
      int bj = (int)(0xFFFFFFFFu - (unsigned)(s_red[0] & 0xFFFFFFFFull));
      topk[(size_t)i * K_TOP + r] = bj;
      s_sim[bj] = -INFINITY;   // remove from future rounds
    }
    __syncthreads();
  }
}

// C[10000,256] = A[10000,128] @ B[128,256]. 16 rows/block, blockDim (256,2).
__global__ __launch_bounds__(512) void gemm1_kernel(
    const float* __restrict__ A, const float* __restrict__ B, float* __restrict__ Cc) {
  __shared__ float As[16][IN_DIM];   // 8 KB
  int r0 = blockIdx.x * 16;
  int tid = threadIdx.y * 256 + threadIdx.x;   // 0..511
  {
    int rr = tid >> 5;      // 32 float4 per row
    int kk = tid & 31;
    ((float4*)&As[rr][0])[kk] = ((const float4*)(A + (size_t)(r0 + rr) * IN_DIM))[kk];
  }
  __syncthreads();
  int col = threadIdx.x;     // 0..255
  int y = threadIdx.y;       // 0..1 -> rows y*8 .. y*8+7
  float acc[8] = {0, 0, 0, 0, 0, 0, 0, 0};
#pragma unroll 4
  for (int k = 0; k < IN_DIM; k++) {
    float bv = B[(size_t)k * D1 + col];
#pragma unroll
    for (int r = 0; r < 8; r++) acc[r] = fmaf(As[y * 8 + r][k], bv, acc[r]);
  }
#pragma unroll
  for (int r = 0; r < 8; r++)
    Cc[(size_t)(r0 + y * 8 + r) * D1 + col] = acc[r];
}

// C[10000,64] = A[10000,256] @ B[256,64]. 16 rows/block, blockDim (64,4).
__global__ __launch_bounds__(256) void gemm2_kernel(
    const float* __restrict__ A, const float* __restrict__ B, float* __restrict__ Cc) {
  __shared__ float As[16][D1];   // 16 KB
  int r0 = blockIdx.x * 16;
  int tid = threadIdx.y * 64 + threadIdx.x;   // 0..255
  for (int e = tid; e < 16 * (D1 / 4); e += 256) {
    int rr = e >> 6;        // 64 float4 per row
    int kk = e & 63;
    ((float4*)&As[rr][0])[kk] = ((const float4*)(A + (size_t)(r0 + rr) * D1))[kk];
  }
  __syncthreads();
  int col = threadIdx.x;     // 0..63
  int y = threadIdx.y;       // 0..3 -> rows y*4..y*4+3
  float acc[4] = {0, 0, 0, 0};
#pragma unroll 4
  for (int k = 0; k < D1; k++) {
    float bv = B[(size_t)k * CDIM + col];
#pragma unroll
    for (int r = 0; r < 4; r++) acc[r] = fmaf(As[y * 4 + r][k], bv, acc[r]);
  }
#pragma unroll
  for (int r = 0; r < 4; r++)
    Cc[(size_t)(r0 + y * 4 + r) * CDIM + col] = acc[r];
}

// e1s/e1t[n][h] = sum_c h1p[n][h*64+c] * a[h*64+c]; one block/node, wave h per head.
__global__ __launch_bounds__(256) void e1_kernel(
    const float* __restrict__ h1p, const float* __restrict__ a_src,
    const float* __restrict__ a_tgt, float* __restrict__ es, float* __restrict__ et) {
  int n = blockIdx.x;
  int tid = threadIdx.x;
  int w = tid >> 6, c = tid & 63;
  float hv = h1p[(size_t)n * D1 + tid];
  float ps = hv * a_src[tid];
  float pt = hv * a_tgt[tid];
#pragma unroll
  for (int off = 32; off > 0; off >>= 1) {
    ps += __shfl_down(ps, off);
    pt += __shfl_down(pt, off);
  }
  if (c == 0) {
    es[(size_t)n * H1 + w] = ps;
    et[(size_t)n * H1 + w] = pt;
  }
}

// GAT layer-1 aggregation: one block per node; thread = (head, channel).
__global__ __launch_bounds__(256) void agg1_kernel(
    const float* __restrict__ h1p, const float* __restrict__ es,
    const float* __restrict__ et, const int* __restrict__ topk,
    const float* __restrict__ b1, float* __restrict__ h1o) {
  int i = blockIdx.x;
  int tid = threadIdx.x;
  __shared__ int nb[NEIGH];
  __shared__ float lg[NEIGH][H1];
  if (tid < K_TOP) nb[tid] = topk[(size_t)i * K_TOP + tid];
  else if (tid == K_TOP) nb[K_TOP] = i;   // self loop appended last (ref order)
  __syncthreads();
  if (tid < NEIGH * H1) {
    int e = tid & 3, jj = tid >> 2;
    float L = es[(size_t)i * H1 + e] + et[(size_t)nb[jj] * H1 + e];
    lg[jj][e] = (L > 0.f) ? L : 0.2f * L;   // leaky_relu 0.2
  }
  __syncthreads();
  int h = tid >> 6;
  float m = -INFINITY;
#pragma unroll
  for (int jj = 0; jj < NEIGH; jj++) m = fmaxf(m, lg[jj][h]);
  float z = 0.f, acc = 0.f;
#pragma unroll
  for (int jj = 0; jj < NEIGH; jj++) {
    float w = expf(lg[jj][h] - m);
    z += w;
    acc = fmaf(w, h1p[(size_t)nb[jj] * D1 + tid], acc);
  }
  float o = acc / z + b1[tid];
  h1o[(size_t)i * D1 + tid] = fmaxf(o, 0.f);
}

// e2s/e2t[n] = sum_c h2p[n][c]*a2[c]; 4 nodes per 256-thread block (one wave each).
__global__ __launch_bounds__(256) void e2_kernel(
    const float* __restrict__ h2p, const float* __restrict__ a_src,
    const float* __restrict__ a_tgt, float* __restrict__ es, float* __restrict__ et) {
  int tid = threadIdx.x;
  int n = blockIdx.x * 4 + (tid >> 6);
  int c = tid & 63;
  float hv = h2p[(size_t)n * CDIM + c];
  float ps = hv * a_src[c];
  float pt = hv * a_tgt[c];
#pragma unroll
  for (int off = 32; off > 0; off >>= 1) {
    ps += __shfl_down(ps, off);
    pt += __shfl_down(pt, off);
  }
  if (c == 0) { es[n] = ps; et[n] = pt; }
}

// GAT layer-2 aggregation + b2: 4 nodes per block, 64 lanes (channels) per node.
__global__ __launch_bounds__(256) void agg2_kernel(
    const float* __restrict__ h2p, const float* __restrict__ es,
    const float* __restrict__ et, const int* __restrict__ topk,
    const float* __restrict__ b2, float* __restrict__ out) {
  int tid = threadIdx.x;
  int li = tid >> 6;
  int c = tid & 63;
  int i = blockIdx.x * 4 + li;
  __shared__ int nb[4][NEIGH];
  __shared__ float lg[4][NEIGH];
  if (tid < 4 * NEIGH) {
    int li2 = tid / NEIGH, jj = tid % NEIGH;
    int node = blockIdx.x * 4 + li2;
    nb[li2][jj] = (jj < K_TOP) ? topk[(size_t)node * K_TOP + jj] : node;
  }
  __syncthreads();
  if (tid < 4 * NEIGH) {
    int li2 = tid / NEIGH, jj = tid % NEIGH;
    int node = blockIdx.x * 4 + li2;
    float L = es[node] + et[nb[li2][jj]];
    lg[li2][jj] = (L > 0.f) ? L : 0.2f * L;
  }
  __syncthreads();
  float m = -INFINITY;
#pragma unroll
  for (int jj = 0; jj < NEIGH; jj++) m = fmaxf(m, lg[li][jj]);
  float z = 0.f, acc = 0.f;
#pragma unroll
  for (int jj = 0; jj < NEIGH; jj++) {
    float w = expf(lg[li][jj] - m);
    z += w;
    acc = fmaf(w, h2p[(size_t)nb[li][jj] * CDIM + c], acc);
  }
  out[(size_t)i * CDIM + c] = acc / z + b2[c];
}

extern "C" void kernel_launch(void* const* d_in, const int* in_sizes, int n_in,
                              void* d_out, int out_size, void* d_ws, size_t ws_size,
                              hipStream_t stream) {
  const float* x   = (const float*)d_in[0];
  const float* emb = (const float*)d_in[1];
  const float* W1  = (const float*)d_in[2];
  const float* a1s = (const float*)d_in[3];
  const float* a1t = (const float*)d_in[4];
  const float* b1  = (const float*)d_in[5];
  const float* W2  = (const float*)d_in[6];
  const float* a2s = (const float*)d_in[7];
  const float* a2t = (const float*)d_in[8];
  const float* b2  = (const float*)d_in[9];
  float* out = (float*)d_out;

  // workspace layout (~24.9 MB total)
  size_t off = 0;
  auto alloc = [&](size_t bytes) {
    void* p = (char*)d_ws + off;
    off += (bytes + 255) & ~(size_t)255;
    return p;
  };
  float* nrm  = (float*)alloc((size_t)N_NODES * EMB_D * sizeof(float));
  int*   topk = (int*)  alloc((size_t)N_NODES * K_TOP * sizeof(int));
  float* h1p  = (float*)alloc((size_t)N_NODES * D1 * sizeof(float));
  float* e1s  = (float*)alloc((size_t)N_NODES * H1 * sizeof(float));
  float* e1t  = (float*)alloc((size_t)N_NODES * H1 * sizeof(float));
  float* h1   = (float*)alloc((size_t)N_NODES * D1 * sizeof(float));
  float* h2p  = (float*)alloc((size_t)N_NODES * CDIM * sizeof(float));
  float* e2s  = (float*)alloc((size_t)N_NODES * sizeof(float));
  float* e2t  = (float*)alloc((size_t)N_NODES * sizeof(float));
  (void)ws_size; (void)in_sizes; (void)n_in; (void)out_size;

  normalize_kernel<<<(N_NODES + 255) / 256, 256, 0, stream>>>(emb, nrm);
  sim_topk_kernel<<<N_NODES, 256, 0, stream>>>(nrm, topk);
  gemm1_kernel<<<N_NODES / 16, dim3(256, 2), 0, stream>>>(x, W1, h1p);
  e1_kernel<<<N_NODES, 256, 0, stream>>>(h1p, a1s, a1t, e1s, e1t);
  agg1_kernel<<<N_NODES, 256, 0, stream>>>(h1p, e1s, e1t, topk, b1, h1);
  gemm2_kernel<<<N_NODES / 16, dim3(64, 4), 0, stream>>>(h1, W2, h2p);
  e2_kernel<<<N_NODES / 4, 256, 0, stream>>>(h2p, a2s, a2t, e2s, e2t);
  agg2_kernel<<<N_NODES / 4, 256, 0, stream>>>(h2p, e2s, e2t, topk, b2, out);
}

// Round 2
// 557.240 us; speedup vs baseline: 1.5754x; 1.5754x over previous
//
#include <hip/hip_runtime.h>
#include <math.h>

// SpatialProcessor: 2-layer GAT over top-K cosine-sim graph. All f32.
// R1 -> R2 change: sim_topk rewritten from 20-round O(20N) block argmax to
// O(N) two-level 256-bin histogram select on u16 key prefixes + exact
// recompute/rank of ~M boundary candidates. 2 rows per 512-thread block.

#define N_NODES 10000
#define EMB_D   16
#define IN_DIM  128
#define H1      4
#define CDIM    64
#define D1      256   // 4*64
#define K_TOP   20
#define NEIGH   21    // K_TOP + self loop
#define CAP     256   // candidate capacity per row (M>CAP -> exact fallback)

__device__ __forceinline__ unsigned monokey(float v) {
  unsigned u = __float_as_uint(v);
  return (u & 0x80000000u) ? ~u : (u | 0x80000000u);
}

// Fixed-order fmaf dot; MUST be bit-identical at every call site.
__device__ __forceinline__ float dot16v(const float* q, float4 v0, float4 v1,
                                        float4 v2, float4 v3) {
  float a = 0.f;
  a = fmaf(q[0],  v0.x, a); a = fmaf(q[1],  v0.y, a);
  a = fmaf(q[2],  v0.z, a); a = fmaf(q[3],  v0.w, a);
  a = fmaf(q[4],  v1.x, a); a = fmaf(q[5],  v1.y, a);
  a = fmaf(q[6],  v1.z, a); a = fmaf(q[7],  v1.w, a);
  a = fmaf(q[8],  v2.x, a); a = fmaf(q[9],  v2.y, a);
  a = fmaf(q[10], v2.z, a); a = fmaf(q[11], v2.w, a);
  a = fmaf(q[12], v3.x, a); a = fmaf(q[13], v3.y, a);
  a = fmaf(q[14], v3.z, a); a = fmaf(q[15], v3.w, a);
  return a;
}

__global__ __launch_bounds__(256) void normalize_kernel(
    const float* __restrict__ emb, float* __restrict__ nrm) {
  int i = blockIdx.x * 256 + threadIdx.x;
  if (i >= N_NODES) return;
  const float4* p = (const float4*)(emb + (size_t)i * EMB_D);
  float4 v[4];
  float ss = 0.f;
#pragma unroll
  for (int k = 0; k < 4; k++) {
    v[k] = p[k];
    ss = fmaf(v[k].x, v[k].x, ss);
    ss = fmaf(v[k].y, v[k].y, ss);
    ss = fmaf(v[k].z, v[k].z, ss);
    ss = fmaf(v[k].w, v[k].w, ss);
  }
  float nv = sqrtf(ss);
  float4* o = (float4*)(nrm + (size_t)i * EMB_D);
#pragma unroll
  for (int k = 0; k < 4; k++) {
    float4 t;
    t.x = v[k].x / nv; t.y = v[k].y / nv; t.z = v[k].z / nv; t.w = v[k].w / nv;
    o[k] = t;
  }
}

// 2 rows per block (512 threads). group g = tid>>8 owns row row0+g.
__global__ __launch_bounds__(512) void sim_topk_kernel(
    const float* __restrict__ nrm, int* __restrict__ topk) {
  __shared__ unsigned short s_k16[2][N_NODES];     // 40000 B: u16 key prefixes
  __shared__ unsigned s_hist[2][256];              // 2048 B
  __shared__ unsigned s_hist2[2][256];             // 2048 B
  __shared__ float s_q[2][EMB_D];                  // 128 B
  __shared__ int s_cand[2][CAP];                   // 2048 B
  __shared__ unsigned long long s_ckey[2][CAP];    // 4096 B (also fallback tree)
  __shared__ int s_cnt[2];
  __shared__ unsigned s_b1[2], s_gt1[2];
  __shared__ unsigned s_p20[2], s_M[2];
  __shared__ int s_fb;

  int tid = threadIdx.x;
  int g = tid >> 8;      // 0/1
  int t = tid & 255;
  int row0 = blockIdx.x * 2;

  if (tid < 2 * EMB_D) {
    int gg = tid >> 4, kk = tid & 15;
    s_q[gg][kk] = nrm[(size_t)(row0 + gg) * EMB_D + kk];
  }
  s_hist[g][t] = 0u;
  s_hist2[g][t] = 0u;
  if (t == 0) s_cnt[g] = 0;
  if (tid == 0) s_fb = 0;
  __syncthreads();

  float qa[EMB_D], qb[EMB_D];
#pragma unroll
  for (int k = 0; k < EMB_D; k++) { qa[k] = s_q[0][k]; qb[k] = s_q[1][k]; }

  // Pass 1: sims for both rows, store u16 monotonic key prefixes.
  for (int j = tid; j < N_NODES; j += 512) {
    const float4* pj = (const float4*)(nrm + (size_t)j * EMB_D);
    float4 v0 = pj[0], v1 = pj[1], v2 = pj[2], v3 = pj[3];
    float A = dot16v(qa, v0, v1, v2, v3);
    float B = dot16v(qb, v0, v1, v2, v3);
    s_k16[0][j] = (unsigned short)(monokey(A) >> 16);
    s_k16[1][j] = (unsigned short)(monokey(B) >> 16);
  }
  __syncthreads();

  // Hist level 1: top 8 bits of u16 key.
  for (int j = t; j < N_NODES; j += 256)
    atomicAdd(&s_hist[g][(unsigned)s_k16[g][j] >> 8], 1u);
  __syncthreads();

  // Suffix scan over 256 bins (one wave per group): find bin containing rank-20.
  if (t < 64) {
    const unsigned* hist = s_hist[g];
    unsigned c0 = hist[4*t+0], c1 = hist[4*t+1], c2 = hist[4*t+2], c3 = hist[4*t+3];
    unsigned s3 = c3, s2 = c2 + s3, s1 = c1 + s2, s0 = c0 + s1;
    unsigned tot = s0, suf = tot;
#pragma unroll
    for (int off = 1; off < 64; off <<= 1) {
      unsigned v = __shfl_down(suf, off);
      if (t + off < 64) suf += v;
    }
    unsigned above = suf - tot;
    unsigned sarr[5] = {s0, s1, s2, s3, 0u};
#pragma unroll
    for (int k = 0; k < 4; k++) {
      unsigned gt = above + sarr[k + 1];
      unsigned ge = above + sarr[k];
      if (gt < K_TOP && ge >= K_TOP) { s_b1[g] = 4*t + k; s_gt1[g] = gt; }
    }
  }
  __syncthreads();

  // Hist level 2: low 8 bits among elements whose high byte == b1.
  unsigned b1 = s_b1[g];
  unsigned tgt2 = K_TOP - s_gt1[g];   // in [1,20]
  for (int j = t; j < N_NODES; j += 256) {
    unsigned kk = (unsigned)s_k16[g][j];
    if ((kk >> 8) == b1) atomicAdd(&s_hist2[g][kk & 255u], 1u);
  }
  __syncthreads();

  if (t < 64) {
    const unsigned* hist = s_hist2[g];
    unsigned c0 = hist[4*t+0], c1 = hist[4*t+1], c2 = hist[4*t+2], c3 = hist[4*t+3];
    unsigned s3 = c3, s2 = c2 + s3, s1 = c1 + s2, s0 = c0 + s1;
    unsigned tot = s0, suf = tot;
#pragma unroll
    for (int off = 1; off < 64; off <<= 1) {
      unsigned v = __shfl_down(suf, off);
      if (t + off < 64) suf += v;
    }
    unsigned above = suf - tot;
    unsigned sarr[5] = {s0, s1, s2, s3, 0u};
#pragma unroll
    for (int k = 0; k < 4; k++) {
      unsigned gt = above + sarr[k + 1];
      unsigned ge = above + sarr[k];
      if (gt < tgt2 && ge >= tgt2) {
        unsigned b2 = 4*t + k;
        unsigned p20 = (b1 << 8) | b2;
        unsigned M = s_gt1[g] + gt + hist[b2];   // #(>p20) + #(==p20)
        s_p20[g] = p20;
        s_M[g] = M;
        if (M > CAP) s_fb = 1;
      }
    }
  }
  __syncthreads();

  unsigned p20 = s_p20[g];
  int M = (int)s_M[g];
  int fb = s_fb;   // block-uniform

  if (!fb) {
    // Collect all candidates with key prefix >= p20 (superset of true top-20).
    for (int j = t; j < N_NODES; j += 256) {
      if ((unsigned)s_k16[g][j] >= p20) {
        int slot = atomicAdd(&s_cnt[g], 1);
        s_cand[g][slot] = j;
      }
    }
    __syncthreads();
    // Exact f32 keys for candidates (bit-identical dot), then rank-by-count.
    if (t < M) {
      int j = s_cand[g][t];
      const float4* pj = (const float4*)(nrm + (size_t)j * EMB_D);
      float4 v0 = pj[0], v1 = pj[1], v2 = pj[2], v3 = pj[3];
      float sim = dot16v(&s_q[g][0], v0, v1, v2, v3);
      s_ckey[g][t] = ((unsigned long long)monokey(sim) << 32) |
                     (unsigned long long)(0xFFFFFFFFu - (unsigned)j);
    }
    __syncthreads();
    if (t < M) {
      unsigned long long mykey = s_ckey[g][t];
      int rank = 0;
      for (int c = 0; c < M; c++) rank += (s_ckey[g][c] > mykey) ? 1 : 0;
      if (rank < K_TOP)
        topk[(size_t)(row0 + g) * K_TOP + rank] = s_cand[g][t];
    }
  } else {
    // Exact fallback (pathological tie mass): 20 rounds of block argmax over
    // candidates >= p20, sims recomputed on the fly. Block-uniform barriers.
    const float* qg = &s_q[g][0];
    for (int r = 0; r < K_TOP; r++) {
      unsigned long long best = 0ull;
      for (int j = t; j < N_NODES; j += 256) {
        if ((unsigned)s_k16[g][j] >= p20) {
          const float4* pj = (const float4*)(nrm + (size_t)j * EMB_D);
          float4 v0 = pj[0], v1 = pj[1], v2 = pj[2], v3 = pj[3];
          float sim = dot16v(qg, v0, v1, v2, v3);
          unsigned long long key = ((unsigned long long)monokey(sim) << 32) |
                                   (unsigned long long)(0xFFFFFFFFu - (unsigned)j);
          if (key > best) best = key;
        }
      }
      s_ckey[g][t] = best;
      __syncthreads();
      for (int s = 128; s > 0; s >>= 1) {
        if (t < s) {
          unsigned long long o = s_ckey[g][t + s];
          if (o > s_ckey[g][t]) s_ckey[g][t] = o;
        }
        __syncthreads();
      }
      if (t == 0) {
        int bj = (int)(0xFFFFFFFFu - (unsigned)(s_ckey[g][0] & 0xFFFFFFFFull));
        topk[(size_t)(row0 + g) * K_TOP + r] = bj;
        s_k16[g][bj] = 0;   // remove winner
      }
      __syncthreads();
    }
  }
}

// C[10000,256] = A[10000,128] @ B[128,256]. 16 rows/block, blockDim (256,2).
__global__ __launch_bounds__(512) void gemm1_kernel(
    const float* __restrict__ A, const float* __restrict__ B, float* __restrict__ Cc) {
  __shared__ float As[16][IN_DIM];
  int r0 = blockIdx.x * 16;
  int tid = threadIdx.y * 256 + threadIdx.x;
  {
    int rr = tid >> 5;
    int kk = tid & 31;
    ((float4*)&As[rr][0])[kk] = ((const float4*)(A + (size_t)(r0 + rr) * IN_DIM))[kk];
  }
  __syncthreads();
  int col = threadIdx.x;
  int y = threadIdx.y;
  float acc[8] = {0, 0, 0, 0, 0, 0, 0, 0};
#pragma unroll 4
  for (int k = 0; k < IN_DIM; k++) {
    float bv = B[(size_t)k * D1 + col];
#pragma unroll
    for (int r = 0; r < 8; r++) acc[r] = fmaf(As[y * 8 + r][k], bv, acc[r]);
  }
#pragma unroll
  for (int r = 0; r < 8; r++)
    Cc[(size_t)(r0 + y * 8 + r) * D1 + col] = acc[r];
}

// C[10000,64] = A[10000,256] @ B[256,64]. 16 rows/block, blockDim (64,4).
__global__ __launch_bounds__(256) void gemm2_kernel(
    const float* __restrict__ A, const float* __restrict__ B, float* __restrict__ Cc) {
  __shared__ float As[16][D1];
  int r0 = blockIdx.x * 16;
  int tid = threadIdx.y * 64 + threadIdx.x;
  for (int e = tid; e < 16 * (D1 / 4); e += 256) {
    int rr = e >> 6;
    int kk = e & 63;
    ((float4*)&As[rr][0])[kk] = ((const float4*)(A + (size_t)(r0 + rr) * D1))[kk];
  }
  __syncthreads();
  int col = threadIdx.x;
  int y = threadIdx.y;
  float acc[4] = {0, 0, 0, 0};
#pragma unroll 4
  for (int k = 0; k < D1; k++) {
    float bv = B[(size_t)k * CDIM + col];
#pragma unroll
    for (int r = 0; r < 4; r++) acc[r] = fmaf(As[y * 4 + r][k], bv, acc[r]);
  }
#pragma unroll
  for (int r = 0; r < 4; r++)
    Cc[(size_t)(r0 + y * 4 + r) * CDIM + col] = acc[r];
}

__global__ __launch_bounds__(256) void e1_kernel(
    const float* __restrict__ h1p, const float* __restrict__ a_src,
    const float* __restrict__ a_tgt, float* __restrict__ es, float* __restrict__ et) {
  int n = blockIdx.x;
  int tid = threadIdx.x;
  int w = tid >> 6, c = tid & 63;
  float hv = h1p[(size_t)n * D1 + tid];
  float ps = hv * a_src[tid];
  float pt = hv * a_tgt[tid];
#pragma unroll
  for (int off = 32; off > 0; off >>= 1) {
    ps += __shfl_down(ps, off);
    pt += __shfl_down(pt, off);
  }
  if (c == 0) {
    es[(size_t)n * H1 + w] = ps;
    et[(size_t)n * H1 + w] = pt;
  }
}

__global__ __launch_bounds__(256) void agg1_kernel(
    const float* __restrict__ h1p, const float* __restrict__ es,
    const float* __restrict__ et, const int* __restrict__ topk,
    const float* __restrict__ b1, float* __restrict__ h1o) {
  int i = blockIdx.x;
  int tid = threadIdx.x;
  __shared__ int nb[NEIGH];
  __shared__ float lg[NEIGH][H1];
  if (tid < K_TOP) nb[tid] = topk[(size_t)i * K_TOP + tid];
  else if (tid == K_TOP) nb[K_TOP] = i;
  __syncthreads();
  if (tid < NEIGH * H1) {
    int e = tid & 3, jj = tid >> 2;
    float L = es[(size_t)i * H1 + e] + et[(size_t)nb[jj] * H1 + e];
    lg[jj][e] = (L > 0.f) ? L : 0.2f * L;
  }
  __syncthreads();
  int h = tid >> 6;
  float m = -INFINITY;
#pragma unroll
  for (int jj = 0; jj < NEIGH; jj++) m = fmaxf(m, lg[jj][h]);
  float z = 0.f, acc = 0.f;
#pragma unroll
  for (int jj = 0; jj < NEIGH; jj++) {
    float w = expf(lg[jj][h] - m);
    z += w;
    acc = fmaf(w, h1p[(size_t)nb[jj] * D1 + tid], acc);
  }
  float o = acc / z + b1[tid];
  h1o[(size_t)i * D1 + tid] = fmaxf(o, 0.f);
}

__global__ __launch_bounds__(256) void e2_kernel(
    const float* __restrict__ h2p, const float* __restrict__ a_src,
    const float* __restrict__ a_tgt, float* __restrict__ es, float* __restrict__ et) {
  int tid = threadIdx.x;
  int n = blockIdx.x * 4 + (tid >> 6);
  int c = tid & 63;
  float hv = h2p[(size_t)n * CDIM + c];
  float ps = hv * a_src[c];
  float pt = hv * a_tgt[c];
#pragma unroll
  for (int off = 32; off > 0; off >>= 1) {
    ps += __shfl_down(ps, off);
    pt += __shfl_down(pt, off);
  }
  if (c == 0) { es[n] = ps; et[n] = pt; }
}

__global__ __launch_bounds__(256) void agg2_kernel(
    const float* __restrict__ h2p, const float* __restrict__ es,
    const float* __restrict__ et, const int* __restrict__ topk,
    const float* __restrict__ b2, float* __restrict__ out) {
  int tid = threadIdx.x;
  int li = tid >> 6;
  int c = tid & 63;
  int i = blockIdx.x * 4 + li;
  __shared__ int nb[4][NEIGH];
  __shared__ float lg[4][NEIGH];
  if (tid < 4 * NEIGH) {
    int li2 = tid / NEIGH, jj = tid % NEIGH;
    int node = blockIdx.x * 4 + li2;
    nb[li2][jj] = (jj < K_TOP) ? topk[(size_t)node * K_TOP + jj] : node;
  }
  __syncthreads();
  if (tid < 4 * NEIGH) {
    int li2 = tid / NEIGH, jj = tid % NEIGH;
    int node = blockIdx.x * 4 + li2;
    float L = es[node] + et[nb[li2][jj]];
    lg[li2][jj] = (L > 0.f) ? L : 0.2f * L;
  }
  __syncthreads();
  float m = -INFINITY;
#pragma unroll
  for (int jj = 0; jj < NEIGH; jj++) m = fmaxf(m, lg[li][jj]);
  float z = 0.f, acc = 0.f;
#pragma unroll
  for (int jj = 0; jj < NEIGH; jj++) {
    float w = expf(lg[li][jj] - m);
    z += w;
    acc = fmaf(w, h2p[(size_t)nb[li][jj] * CDIM + c], acc);
  }
  out[(size_t)i * CDIM + c] = acc / z + b2[c];
}

extern "C" void kernel_launch(void* const* d_in, const int* in_sizes, int n_in,
                              void* d_out, int out_size, void* d_ws, size_t ws_size,
                              hipStream_t stream) {
  const float* x   = (const float*)d_in[0];
  const float* emb = (const float*)d_in[1];
  const float* W1  = (const float*)d_in[2];
  const float* a1s = (const float*)d_in[3];
  const float* a1t = (const float*)d_in[4];
  const float* b1  = (const float*)d_in[5];
  const float* W2  = (const float*)d_in[6];
  const float* a2s = (const float*)d_in[7];
  const float* a2t = (const float*)d_in[8];
  const float* b2  = (const float*)d_in[9];
  float* out = (float*)d_out;

  size_t off = 0;
  auto alloc = [&](size_t bytes) {
    void* p = (char*)d_ws + off;
    off += (bytes + 255) & ~(size_t)255;
    return p;
  };
  float* nrm  = (float*)alloc((size_t)N_NODES * EMB_D * sizeof(float));
  int*   topk = (int*)  alloc((size_t)N_NODES * K_TOP * sizeof(int));
  float* h1p  = (float*)alloc((size_t)N_NODES * D1 * sizeof(float));
  float* e1s  = (float*)alloc((size_t)N_NODES * H1 * sizeof(float));
  float* e1t  = (float*)alloc((size_t)N_NODES * H1 * sizeof(float));
  float* h1   = (float*)alloc((size_t)N_NODES * D1 * sizeof(float));
  float* h2p  = (float*)alloc((size_t)N_NODES * CDIM * sizeof(float));
  float* e2s  = (float*)alloc((size_t)N_NODES * sizeof(float));
  float* e2t  = (float*)alloc((size_t)N_NODES * sizeof(float));
  (void)ws_size; (void)in_sizes; (void)n_in; (void)out_size;

  normalize_kernel<<<(N_NODES + 255) / 256, 256, 0, stream>>>(emb, nrm);
  sim_topk_kernel<<<N_NODES / 2, 512, 0, stream>>>(nrm, topk);
  gemm1_kernel<<<N_NODES / 16, dim3(256, 2), 0, stream>>>(x, W1, h1p);
  e1_kernel<<<N_NODES, 256, 0, stream>>>(h1p, a1s, a1t, e1s, e1t);
  agg1_kernel<<<N_NODES, 256, 0, stream>>>(h1p, e1s, e1t, topk, b1, h1);
  gemm2_kernel<<<N_NODES / 16, dim3(64, 4), 0, stream>>>(h1, W2, h2p);
  e2_kernel<<<N_NODES / 4, 256, 0, stream>>>(h2p, a2s, a2t, e2s, e2t);
  agg2_kernel<<<N_NODES / 4, 256, 0, stream>>>(h2p, e2s, e2t, topk, b2, out);
}

// Round 3
// 332.354 us; speedup vs baseline: 2.6414x; 1.6766x over previous
//
#include <hip/hip_runtime.h>
#include <math.h>

// SpatialProcessor: 2-layer GAT over top-K cosine-sim graph. All f32.
// R2 -> R3: sim_topk restructured to histogram-select WITHOUT storing keys:
//   pass1 recompute-sims -> per-row 256-bin linear histogram (LDS, atomics)
//   wave-per-row suffix scan -> exact threshold bin + candidate count M
//   pass2 recompute-sims -> collect M candidates + exact u64 keys
//   rank-by-count among M (<=128) -> exact (sim desc, idx asc) top-20
// LDS 50.6KB -> ~21KB, no per-element LDS stores, no serial block phases.

#define N_NODES 10000
#define EMB_D   16
#define IN_DIM  128
#define H1      4
#define CDIM    64
#define D1      256   // 4*64
#define K_TOP   20
#define NEIGH   21    // K_TOP + self loop
#define RPB     8     // rows per sim block
#define TPB     512
#define CAP     128   // candidate capacity per row (M>CAP -> exact fallback)

__device__ __forceinline__ unsigned monokey(float v) {
  unsigned u = __float_as_uint(v);
  return (u & 0x80000000u) ? ~u : (u | 0x80000000u);
}

// Linear monotonic bucket over [-1, 1]; identical codegen at every call site.
__device__ __forceinline__ int bucket_of(float sim) {
  float bf = fmaf(sim, 128.0f, 128.0f);
  int b = (int)bf;
  b = b < 0 ? 0 : b;
  return b > 255 ? 255 : b;
}

// Fixed-order fmaf dot; MUST be bit-identical at every call site.
__device__ __forceinline__ float dot16q(float4 qa, float4 qb, float4 qc, float4 qd,
                                        float4 v0, float4 v1, float4 v2, float4 v3) {
  float a = 0.f;
  a = fmaf(qa.x, v0.x, a); a = fmaf(qa.y, v0.y, a);
  a = fmaf(qa.z, v0.z, a); a = fmaf(qa.w, v0.w, a);
  a = fmaf(qb.x, v1.x, a); a = fmaf(qb.y, v1.y, a);
  a = fmaf(qb.z, v1.z, a); a = fmaf(qb.w, v1.w, a);
  a = fmaf(qc.x, v2.x, a); a = fmaf(qc.y, v2.y, a);
  a = fmaf(qc.z, v2.z, a); a = fmaf(qc.w, v2.w, a);
  a = fmaf(qd.x, v3.x, a); a = fmaf(qd.y, v3.y, a);
  a = fmaf(qd.z, v3.z, a); a = fmaf(qd.w, v3.w, a);
  return a;
}

__global__ __launch_bounds__(256) void normalize_kernel(
    const float* __restrict__ emb, float* __restrict__ nrm) {
  int i = blockIdx.x * 256 + threadIdx.x;
  if (i >= N_NODES) return;
  const float4* p = (const float4*)(emb + (size_t)i * EMB_D);
  float4 v[4];
  float ss = 0.f;
#pragma unroll
  for (int k = 0; k < 4; k++) {
    v[k] = p[k];
    ss = fmaf(v[k].x, v[k].x, ss);
    ss = fmaf(v[k].y, v[k].y, ss);
    ss = fmaf(v[k].z, v[k].z, ss);
    ss = fmaf(v[k].w, v[k].w, ss);
  }
  float nv = sqrtf(ss);
  float4* o = (float4*)(nrm + (size_t)i * EMB_D);
#pragma unroll
  for (int k = 0; k < 4; k++) {
    float4 t;
    t.x = v[k].x / nv; t.y = v[k].y / nv; t.z = v[k].z / nv; t.w = v[k].w / nv;
    o[k] = t;
  }
}

// 8 rows per 512-thread block; grid = 1250.
__global__ __launch_bounds__(TPB) void sim_topk_kernel(
    const float* __restrict__ nrm, int* __restrict__ topk) {
  __shared__ float s_q[RPB][EMB_D];                // 512 B
  __shared__ unsigned s_hist[RPB][256];            // 8 KB
  __shared__ int s_cand[RPB][CAP];                 // 4 KB
  __shared__ unsigned long long s_ckey[RPB][CAP];  // 8 KB
  __shared__ int s_cnt[RPB];
  __shared__ int s_thr[RPB];
  __shared__ unsigned s_M[RPB];

  int tid = threadIdx.x;
  int row0 = blockIdx.x * RPB;

  for (int idx = tid; idx < RPB * 256; idx += TPB) ((unsigned*)s_hist)[idx] = 0u;
  if (tid < RPB * EMB_D) ((float*)s_q)[tid] = nrm[(size_t)row0 * EMB_D + tid];
  if (tid < RPB) s_cnt[tid] = 0;
  __syncthreads();

  // ---- Pass 1: histogram of linear buckets (sims recomputed, not stored) ----
  for (int it = 0; it < 5; ++it) {
    int j0 = it * (TPB * 4) + tid * 4;   // 4 consecutive rows per thread
    if (j0 < N_NODES) {                  // 10000 % 4 == 0: all-or-none
      float4 v[4][4];
#pragma unroll
      for (int jj = 0; jj < 4; jj++) {
        const float4* pj = (const float4*)(nrm + (size_t)(j0 + jj) * EMB_D);
        v[jj][0] = pj[0]; v[jj][1] = pj[1]; v[jj][2] = pj[2]; v[jj][3] = pj[3];
      }
#pragma unroll
      for (int r = 0; r < RPB; r++) {
        const float4* qp = (const float4*)&s_q[r][0];
        float4 qa = qp[0], qb = qp[1], qc = qp[2], qd = qp[3];
#pragma unroll
        for (int jj = 0; jj < 4; jj++) {
          float sim = dot16q(qa, qb, qc, qd, v[jj][0], v[jj][1], v[jj][2], v[jj][3]);
          atomicAdd(&s_hist[r][bucket_of(sim)], 1u);
        }
      }
    }
  }
  __syncthreads();

  // ---- Wave-per-row suffix scan: threshold bin + M ----
  {
    int w = tid >> 6, lane = tid & 63;   // 8 waves == RPB rows
    const unsigned* hist = &s_hist[w][0];
    unsigned c0 = hist[4 * lane + 0], c1 = hist[4 * lane + 1];
    unsigned c2 = hist[4 * lane + 2], c3 = hist[4 * lane + 3];
    unsigned s3 = c3, s2 = c2 + s3, s1 = c1 + s2, s0 = c0 + s1;
    unsigned tot = s0, suf = tot;
#pragma unroll
    for (int off = 1; off < 64; off <<= 1) {
      unsigned vv = __shfl_down(suf, off);
      if (lane + off < 64) suf += vv;
    }
    unsigned above = suf - tot;          // count in buckets > 4*lane+3
    unsigned sarr[5] = {s0, s1, s2, s3, 0u};
#pragma unroll
    for (int k = 0; k < 4; k++) {
      unsigned gt = above + sarr[k + 1]; // count strictly above bucket 4*lane+k
      unsigned ge = above + sarr[k];     // count >= bucket
      if (gt < K_TOP && ge >= K_TOP) { s_thr[w] = 4 * lane + k; s_M[w] = ge; }
    }
  }
  __syncthreads();

  // ---- Pass 2: collect candidates (bucket >= thr) with exact keys ----
  for (int it = 0; it < 5; ++it) {
    int j0 = it * (TPB * 4) + tid * 4;
    if (j0 < N_NODES) {
      float4 v[4][4];
#pragma unroll
      for (int jj = 0; jj < 4; jj++) {
        const float4* pj = (const float4*)(nrm + (size_t)(j0 + jj) * EMB_D);
        v[jj][0] = pj[0]; v[jj][1] = pj[1]; v[jj][2] = pj[2]; v[jj][3] = pj[3];
      }
#pragma unroll
      for (int r = 0; r < RPB; r++) {
        if (s_M[r] > CAP) continue;      // fallback row: skip collection
        int thr = s_thr[r];
        const float4* qp = (const float4*)&s_q[r][0];
        float4 qa = qp[0], qb = qp[1], qc = qp[2], qd = qp[3];
#pragma unroll
        for (int jj = 0; jj < 4; jj++) {
          float sim = dot16q(qa, qb, qc, qd, v[jj][0], v[jj][1], v[jj][2], v[jj][3]);
          if (bucket_of(sim) >= thr) {
            int slot = atomicAdd(&s_cnt[r], 1);   // slot < M <= CAP guaranteed
            s_cand[r][slot] = j0 + jj;
            s_ckey[r][slot] = ((unsigned long long)monokey(sim) << 32) |
                              (unsigned long long)(0xFFFFFFFFu - (unsigned)(j0 + jj));
          }
        }
      }
    }
  }
  __syncthreads();

  // ---- Rank-by-count (wave per row); exact fallback if M > CAP ----
  {
    int w = tid >> 6, lane = tid & 63;
    int row = row0 + w;
    int M = (int)s_M[w];
    if (M <= CAP) {
      for (int c = lane; c < M; c += 64) {
        unsigned long long mykey = s_ckey[w][c];
        int rank = 0;
        for (int i = 0; i < M; i++) rank += (s_ckey[w][i] > mykey) ? 1 : 0;
        if (rank < K_TOP) topk[(size_t)row * K_TOP + rank] = s_cand[w][c];
      }
    } else {
      // Exact wave-local fallback: 20 rounds of argmax over keys < prev.
      const float4* qp = (const float4*)&s_q[w][0];
      float4 qa = qp[0], qb = qp[1], qc = qp[2], qd = qp[3];
      unsigned long long prev = ~0ull;
      for (int r = 0; r < K_TOP; r++) {
        unsigned long long best = 0ull;
        for (int j = lane; j < N_NODES; j += 64) {
          const float4* pj = (const float4*)(nrm + (size_t)j * EMB_D);
          float sim = dot16q(qa, qb, qc, qd, pj[0], pj[1], pj[2], pj[3]);
          unsigned long long key = ((unsigned long long)monokey(sim) << 32) |
                                   (unsigned long long)(0xFFFFFFFFu - (unsigned)j);
          if (key < prev && key > best) best = key;
        }
#pragma unroll
        for (int off = 32; off > 0; off >>= 1) {
          unsigned long long o = __shfl_down(best, off);
          if (o > best) best = o;
        }
        best = __shfl(best, 0);
        prev = best;
        if (lane == 0)
          topk[(size_t)row * K_TOP + r] =
              (int)(0xFFFFFFFFu - (unsigned)(best & 0xFFFFFFFFull));
      }
    }
  }
}

// C[10000,256] = A[10000,128] @ B[128,256]. 16 rows/block, blockDim (256,2).
__global__ __launch_bounds__(512) void gemm1_kernel(
    const float* __restrict__ A, const float* __restrict__ B, float* __restrict__ Cc) {
  __shared__ float As[16][IN_DIM];
  int r0 = blockIdx.x * 16;
  int tid = threadIdx.y * 256 + threadIdx.x;
  {
    int rr = tid >> 5;
    int kk = tid & 31;
    ((float4*)&As[rr][0])[kk] = ((const float4*)(A + (size_t)(r0 + rr) * IN_DIM))[kk];
  }
  __syncthreads();
  int col = threadIdx.x;
  int y = threadIdx.y;
  float acc[8] = {0, 0, 0, 0, 0, 0, 0, 0};
#pragma unroll 4
  for (int k = 0; k < IN_DIM; k++) {
    float bv = B[(size_t)k * D1 + col];
#pragma unroll
    for (int r = 0; r < 8; r++) acc[r] = fmaf(As[y * 8 + r][k], bv, acc[r]);
  }
#pragma unroll
  for (int r = 0; r < 8; r++)
    Cc[(size_t)(r0 + y * 8 + r) * D1 + col] = acc[r];
}

// C[10000,64] = A[10000,256] @ B[256,64]. 16 rows/block, blockDim (64,4).
__global__ __launch_bounds__(256) void gemm2_kernel(
    const float* __restrict__ A, const float* __restrict__ B, float* __restrict__ Cc) {
  __shared__ float As[16][D1];
  int r0 = blockIdx.x * 16;
  int tid = threadIdx.y * 64 + threadIdx.x;
  for (int e = tid; e < 16 * (D1 / 4); e += 256) {
    int rr = e >> 6;
    int kk = e & 63;
    ((float4*)&As[rr][0])[kk] = ((const float4*)(A + (size_t)(r0 + rr) * D1))[kk];
  }
  __syncthreads();
  int col = threadIdx.x;
  int y = threadIdx.y;
  float acc[4] = {0, 0, 0, 0};
#pragma unroll 4
  for (int k = 0; k < D1; k++) {
    float bv = B[(size_t)k * CDIM + col];
#pragma unroll
    for (int r = 0; r < 4; r++) acc[r] = fmaf(As[y * 4 + r][k], bv, acc[r]);
  }
#pragma unroll
  for (int r = 0; r < 4; r++)
    Cc[(size_t)(r0 + y * 4 + r) * CDIM + col] = acc[r];
}

__global__ __launch_bounds__(256) void e1_kernel(
    const float* __restrict__ h1p, const float* __restrict__ a_src,
    const float* __restrict__ a_tgt, float* __restrict__ es, float* __restrict__ et) {
  int n = blockIdx.x;
  int tid = threadIdx.x;
  int w = tid >> 6, c = tid & 63;
  float hv = h1p[(size_t)n * D1 + tid];
  float ps = hv * a_src[tid];
  float pt = hv * a_tgt[tid];
#pragma unroll
  for (int off = 32; off > 0; off >>= 1) {
    ps += __shfl_down(ps, off);
    pt += __shfl_down(pt, off);
  }
  if (c == 0) {
    es[(size_t)n * H1 + w] = ps;
    et[(size_t)n * H1 + w] = pt;
  }
}

__global__ __launch_bounds__(256) void agg1_kernel(
    const float* __restrict__ h1p, const float* __restrict__ es,
    const float* __restrict__ et, const int* __restrict__ topk,
    const float* __restrict__ b1, float* __restrict__ h1o) {
  int i = blockIdx.x;
  int tid = threadIdx.x;
  __shared__ int nb[NEIGH];
  __shared__ float lg[NEIGH][H1];
  if (tid < K_TOP) nb[tid] = topk[(size_t)i * K_TOP + tid];
  else if (tid == K_TOP) nb[K_TOP] = i;
  __syncthreads();
  if (tid < NEIGH * H1) {
    int e = tid & 3, jj = tid >> 2;
    float L = es[(size_t)i * H1 + e] + et[(size_t)nb[jj] * H1 + e];
    lg[jj][e] = (L > 0.f) ? L : 0.2f * L;
  }
  __syncthreads();
  int h = tid >> 6;
  float m = -INFINITY;
#pragma unroll
  for (int jj = 0; jj < NEIGH; jj++) m = fmaxf(m, lg[jj][h]);
  float z = 0.f, acc = 0.f;
#pragma unroll
  for (int jj = 0; jj < NEIGH; jj++) {
    float w = expf(lg[jj][h] - m);
    z += w;
    acc = fmaf(w, h1p[(size_t)nb[jj] * D1 + tid], acc);
  }
  float o = acc / z + b1[tid];
  h1o[(size_t)i * D1 + tid] = fmaxf(o, 0.f);
}

__global__ __launch_bounds__(256) void e2_kernel(
    const float* __restrict__ h2p, const float* __restrict__ a_src,
    const float* __restrict__ a_tgt, float* __restrict__ es, float* __restrict__ et) {
  int tid = threadIdx.x;
  int n = blockIdx.x * 4 + (tid >> 6);
  int c = tid & 63;
  float hv = h2p[(size_t)n * CDIM + c];
  float ps = hv * a_src[c];
  float pt = hv * a_tgt[c];
#pragma unroll
  for (int off = 32; off > 0; off >>= 1) {
    ps += __shfl_down(ps, off);
    pt += __shfl_down(pt, off);
  }
  if (c == 0) { es[n] = ps; et[n] = pt; }
}

__global__ __launch_bounds__(256) void agg2_kernel(
    const float* __restrict__ h2p, const float* __restrict__ es,
    const float* __restrict__ et, const int* __restrict__ topk,
    const float* __restrict__ b2, float* __restrict__ out) {
  int tid = threadIdx.x;
  int li = tid >> 6;
  int c = tid & 63;
  int i = blockIdx.x * 4 + li;
  __shared__ int nb[4][NEIGH];
  __shared__ float lg[4][NEIGH];
  if (tid < 4 * NEIGH) {
    int li2 = tid / NEIGH, jj = tid % NEIGH;
    int node = blockIdx.x * 4 + li2;
    nb[li2][jj] = (jj < K_TOP) ? topk[(size_t)node * K_TOP + jj] : node;
  }
  __syncthreads();
  if (tid < 4 * NEIGH) {
    int li2 = tid / NEIGH, jj = tid % NEIGH;
    int node = blockIdx.x * 4 + li2;
    float L = es[node] + et[nb[li2][jj]];
    lg[li2][jj] = (L > 0.f) ? L : 0.2f * L;
  }
  __syncthreads();
  float m = -INFINITY;
#pragma unroll
  for (int jj = 0; jj < NEIGH; jj++) m = fmaxf(m, lg[li][jj]);
  float z = 0.f, acc = 0.f;
#pragma unroll
  for (int jj = 0; jj < NEIGH; jj++) {
    float w = expf(lg[li][jj] - m);
    z += w;
    acc = fmaf(w, h2p[(size_t)nb[li][jj] * CDIM + c], acc);
  }
  out[(size_t)i * CDIM + c] = acc / z + b2[c];
}

extern "C" void kernel_launch(void* const* d_in, const int* in_sizes, int n_in,
                              void* d_out, int out_size, void* d_ws, size_t ws_size,
                              hipStream_t stream) {
  const float* x   = (const float*)d_in[0];
  const float* emb = (const float*)d_in[1];
  const float* W1  = (const float*)d_in[2];
  const float* a1s = (const float*)d_in[3];
  const float* a1t = (const float*)d_in[4];
  const float* b1  = (const float*)d_in[5];
  const float* W2  = (const float*)d_in[6];
  const float* a2s = (const float*)d_in[7];
  const float* a2t = (const float*)d_in[8];
  const float* b2  = (const float*)d_in[9];
  float* out = (float*)d_out;

  size_t off = 0;
  auto alloc = [&](size_t bytes) {
    void* p = (char*)d_ws + off;
    off += (bytes + 255) & ~(size_t)255;
    return p;
  };
  float* nrm  = (float*)alloc((size_t)N_NODES * EMB_D * sizeof(float));
  int*   topk = (int*)  alloc((size_t)N_NODES * K_TOP * sizeof(int));
  float* h1p  = (float*)alloc((size_t)N_NODES * D1 * sizeof(float));
  float* e1s  = (float*)alloc((size_t)N_NODES * H1 * sizeof(float));
  float* e1t  = (float*)alloc((size_t)N_NODES * H1 * sizeof(float));
  float* h1   = (float*)alloc((size_t)N_NODES * D1 * sizeof(float));
  float* h2p  = (float*)alloc((size_t)N_NODES * CDIM * sizeof(float));
  float* e2s  = (float*)alloc((size_t)N_NODES * sizeof(float));
  float* e2t  = (float*)alloc((size_t)N_NODES * sizeof(float));
  (void)ws_size; (void)in_sizes; (void)n_in; (void)out_size;

  normalize_kernel<<<(N_NODES + 255) / 256, 256, 0, stream>>>(emb, nrm);
  sim_topk_kernel<<<N_NODES / RPB, TPB, 0, stream>>>(nrm, topk);
  gemm1_kernel<<<N_NODES / 16, dim3(256, 2), 0, stream>>>(x, W1, h1p);
  e1_kernel<<<N_NODES, 256, 0, stream>>>(h1p, a1s, a1t, e1s, e1t);
  agg1_kernel<<<N_NODES, 256, 0, stream>>>(h1p, e1s, e1t, topk, b1, h1);
  gemm2_kernel<<<N_NODES / 16, dim3(64, 4), 0, stream>>>(h1, W2, h2p);
  e2_kernel<<<N_NODES / 4, 256, 0, stream>>>(h2p, a2s, a2t, e2s, e2t);
  agg2_kernel<<<N_NODES / 4, 256, 0, stream>>>(h2p, e2s, e2t, topk, b2, out);
}